// Round 1
// baseline (742.295 us; speedup 1.0000x reference)
//
#include <hip/hip_runtime.h>
#include <math.h>

// Problem constants (from reference)
#define NM 20301          // mesh points (201*202/2)
#define TT 4096           // time steps
#define NC 16             // chunks over T
#define CH 256            // steps per chunk = TT/NC
#define NBLK 80           // ceil(NM/256)
#define LOG2E_K 1442.69504f   // 1000 * log2(e)  (temp = 0.001)

__device__ __forceinline__ float wave_reduce_sum(float w) {
    #pragma unroll
    for (int off = 32; off > 0; off >>= 1)
        w += __shfl_down(w, off, 64);
    return w;
}

// ---------------- density MLP: [N,2] -> 16 -> 16 -> 16 -> 1 ----------------
__global__ __launch_bounds__(256) void density_kernel(
    const float* __restrict__ alpha, const float* __restrict__ beta,
    const float* __restrict__ w1, const float* __restrict__ b1,
    const float* __restrict__ w2, const float* __restrict__ b2,
    const float* __restrict__ w3, const float* __restrict__ b3,
    const float* __restrict__ w4, const float* __restrict__ b4,
    float* __restrict__ density_out, float* __restrict__ densum)
{
    int n = blockIdx.x * 256 + threadIdx.x;
    bool valid = n < NM;
    int nn = valid ? n : NM - 1;
    float a = alpha[nn], b = beta[nn];

    float h1[16], h2[16], h3[16];
    #pragma unroll
    for (int j = 0; j < 16; j++) {
        float v = fmaf(a, w1[j], fmaf(b, w1[16 + j], b1[j]));
        h1[j] = fmaxf(v, 0.f);
    }
    #pragma unroll
    for (int j = 0; j < 16; j++) {
        float v = b2[j];
        #pragma unroll
        for (int k = 0; k < 16; k++) v = fmaf(h1[k], w2[k * 16 + j], v);
        h2[j] = fmaxf(v, 0.f);
    }
    #pragma unroll
    for (int j = 0; j < 16; j++) {
        float v = b3[j];
        #pragma unroll
        for (int k = 0; k < 16; k++) v = fmaf(h2[k], w3[k * 16 + j], v);
        h3[j] = fmaxf(v, 0.f);
    }
    float v = b4[0];
    #pragma unroll
    for (int k = 0; k < 16; k++) v = fmaf(h3[k], w4[k], v);
    float d = 1.f / (1.f + __expf(-v));

    if (valid) density_out[n] = d;
    float wsum = wave_reduce_sum(valid ? d : 0.f);
    if ((threadIdx.x & 63) == 0) unsafeAtomicAdd(densum, wsum);
}

// ---- pass 1: per-(n,chunk) affine composite  s_end = A + B*s_start --------
__global__ __launch_bounds__(256) void chunk_compose_kernel(
    const float* __restrict__ x, const float* __restrict__ alpha,
    const float* __restrict__ beta,
    float* __restrict__ Abuf, float* __restrict__ Bbuf)
{
    __shared__ float xs[CH];
    int c = blockIdx.y;
    xs[threadIdx.x] = x[c * CH + threadIdx.x] * LOG2E_K;
    __syncthreads();

    int n = blockIdx.x * 256 + threadIdx.x;
    int nn = (n < NM) ? n : NM - 1;
    float ka = alpha[nn] * LOG2E_K;
    float kb = beta[nn] * LOG2E_K;

    float A = 0.f, B = 1.f;
    #pragma unroll 8
    for (int i = 0; i < CH; i++) {
        float ku = xs[i];
        float e1 = __builtin_amdgcn_exp2f(ka - ku);   // exp(-1000*(u-alpha))
        float e2 = __builtin_amdgcn_exp2f(ku - kb);   // exp(-1000*(beta-u))
        float up = __builtin_amdgcn_rcpf(1.f + e1);
        float dn = __builtin_amdgcn_rcpf(1.f + e2);
        float aa = up - dn;
        float bb = (1.f - up) * (1.f - dn);
        A = fmaf(bb, A, aa);
        B *= bb;
    }
    if (n < NM) { Abuf[c * NM + n] = A; Bbuf[c * NM + n] = B; }
}

// ---- pass 2: sequential scan over the 16 chunk boundaries -----------------
__global__ __launch_bounds__(256) void chunk_scan_kernel(
    const float* __restrict__ init_raw,
    const float* __restrict__ Abuf, const float* __restrict__ Bbuf,
    float* __restrict__ sstart)
{
    int n = blockIdx.x * 256 + threadIdx.x;
    if (n >= NM) return;
    float s = tanhf(init_raw[n]);
    #pragma unroll
    for (int c = 0; c < NC; c++) {
        sstart[c * NM + n] = s;                     // state entering chunk c
        s = fmaf(Bbuf[c * NM + n], s, Abuf[c * NM + n]);
    }
}

// ---- pass 3: replay each chunk, store states, reduce density*s ------------
__global__ __launch_bounds__(256) void states_kernel(
    const float* __restrict__ x, const float* __restrict__ alpha,
    const float* __restrict__ beta, const float* __restrict__ density,
    const float* __restrict__ sstart,
    float* __restrict__ states, float* __restrict__ msum)
{
    __shared__ float xs[CH];
    int c = blockIdx.y;
    xs[threadIdx.x] = x[c * CH + threadIdx.x] * LOG2E_K;
    __syncthreads();

    int n = blockIdx.x * 256 + threadIdx.x;
    bool valid = n < NM;
    int nn = valid ? n : NM - 1;
    float ka = alpha[nn] * LOG2E_K;
    float kb = beta[nn] * LOG2E_K;
    float d  = valid ? density[n] : 0.f;
    float s  = sstart[c * NM + nn];
    int lane = threadIdx.x & 63;

    #pragma unroll 4
    for (int i = 0; i < CH; i++) {
        float ku = xs[i];
        float e1 = __builtin_amdgcn_exp2f(ka - ku);
        float e2 = __builtin_amdgcn_exp2f(ku - kb);
        float up = __builtin_amdgcn_rcpf(1.f + e1);
        float dn = __builtin_amdgcn_rcpf(1.f + e2);
        float aa = up - dn;
        float bb = (1.f - up) * (1.f - dn);
        s = fmaf(bb, s, aa);

        int t = c * CH + i;
        if (valid) states[(size_t)t * NM + n] = s;
        float w = wave_reduce_sum(valid ? d * s : 0.f);
        if (lane == 0) unsafeAtomicAdd(&msum[t], w);
    }
}

// ---- pass 4: out[t] = m_scale*m + m_offset + h_scale*x --------------------
__global__ __launch_bounds__(256) void finalize_kernel(
    const float* __restrict__ x, const float* __restrict__ msum,
    const float* __restrict__ densum,
    const float* __restrict__ msr, const float* __restrict__ mor,
    const float* __restrict__ hsr, float* __restrict__ out)
{
    int t = blockIdx.x * 256 + threadIdx.x;
    if (t >= TT) return;
    float sig_ms = 1.f / (1.f + __expf(-msr[0]));
    float sig_mo = 1.f / (1.f + __expf(-mor[0]));
    float sig_hs = 1.f / (1.f + __expf(-hsr[0]));
    float m_scale  = 10.f * sig_ms;
    float m_offset = fmaf(20.f, sig_mo, -10.f);
    float h_scale  = 10.f * sig_hs;
    float m = msum[t] / densum[0];
    out[t] = fmaf(m_scale, m, m_offset) + h_scale * x[t];
}

extern "C" void kernel_launch(void* const* d_in, const int* in_sizes, int n_in,
                              void* d_out, int out_size, void* d_ws, size_t ws_size,
                              hipStream_t stream)
{
    // setup_inputs() dict order:
    const float* x    = (const float*)d_in[0];   // [4096]
    const float* alpha= (const float*)d_in[1];   // [20301]
    const float* beta = (const float*)d_in[2];   // [20301]
    const float* init = (const float*)d_in[3];   // [20301]
    const float* msr  = (const float*)d_in[4];   // [1]
    const float* mor  = (const float*)d_in[5];   // [1]
    const float* hsr  = (const float*)d_in[6];   // [1]
    const float* w1   = (const float*)d_in[7];   // [2,16]
    const float* b1   = (const float*)d_in[8];   // [16]
    const float* w2   = (const float*)d_in[9];   // [16,16]
    const float* b2   = (const float*)d_in[10];  // [16]
    const float* w3   = (const float*)d_in[11];  // [16,16]
    const float* b3   = (const float*)d_in[12];  // [16]
    const float* w4   = (const float*)d_in[13];  // [16,1]
    const float* b4   = (const float*)d_in[14];  // [1]

    float* out     = (float*)d_out;          // [TT]
    float* density = out + TT;               // [NM]
    float* states  = density + NM;           // [TT*NM]

    // workspace: msum[TT] | densum[1] | (pad) | sstart[NC*NM]
    float* msum   = (float*)d_ws;
    float* densum = msum + TT;
    float* sstart = msum + 8192;

    // (A,B) chunk composites stashed in the states region of d_out;
    // they are fully consumed by chunk_scan_kernel before states_kernel
    // overwrites that region.
    float* Abuf = states;
    float* Bbuf = states + (size_t)NC * NM;

    hipMemsetAsync(d_ws, 0, (TT + 64) * sizeof(float), stream);

    density_kernel<<<dim3(NBLK), dim3(256), 0, stream>>>(
        alpha, beta, w1, b1, w2, b2, w3, b3, w4, b4, density, densum);

    chunk_compose_kernel<<<dim3(NBLK, NC), dim3(256), 0, stream>>>(
        x, alpha, beta, Abuf, Bbuf);

    chunk_scan_kernel<<<dim3(NBLK), dim3(256), 0, stream>>>(
        init, Abuf, Bbuf, sstart);

    states_kernel<<<dim3(NBLK, NC), dim3(256), 0, stream>>>(
        x, alpha, beta, density, sstart, states, msum);

    finalize_kernel<<<dim3(TT / 256), dim3(256), 0, stream>>>(
        x, msum, densum, msr, mor, hsr, out);
}

// Round 2
// 593.865 us; speedup vs baseline: 1.2499x; 1.2499x over previous
//
#include <hip/hip_runtime.h>
#include <math.h>

// Problem constants (from reference)
#define NM 20301          // mesh points (201*202/2)
#define TT 4096           // time steps
#define NC 16             // chunks over T
#define CH 256            // steps per chunk = TT/NC
#define NBLK 80           // ceil(NM/256)
#define LOG2E_K 1442.69504f   // 1000 * log2(e)  (temp = 0.001)

__device__ __forceinline__ float wave_reduce_sum(float w) {
    #pragma unroll
    for (int off = 32; off > 0; off >>= 1)
        w += __shfl_down(w, off, 64);
    return w;
}

// ---------------- density MLP: [N,2] -> 16 -> 16 -> 16 -> 1 ----------------
__global__ __launch_bounds__(256) void density_kernel(
    const float* __restrict__ alpha, const float* __restrict__ beta,
    const float* __restrict__ w1, const float* __restrict__ b1,
    const float* __restrict__ w2, const float* __restrict__ b2,
    const float* __restrict__ w3, const float* __restrict__ b3,
    const float* __restrict__ w4, const float* __restrict__ b4,
    float* __restrict__ density_out, float* __restrict__ densum)
{
    int n = blockIdx.x * 256 + threadIdx.x;
    bool valid = n < NM;
    int nn = valid ? n : NM - 1;
    float a = alpha[nn], b = beta[nn];

    float h1[16], h2[16], h3[16];
    #pragma unroll
    for (int j = 0; j < 16; j++) {
        float v = fmaf(a, w1[j], fmaf(b, w1[16 + j], b1[j]));
        h1[j] = fmaxf(v, 0.f);
    }
    #pragma unroll
    for (int j = 0; j < 16; j++) {
        float v = b2[j];
        #pragma unroll
        for (int k = 0; k < 16; k++) v = fmaf(h1[k], w2[k * 16 + j], v);
        h2[j] = fmaxf(v, 0.f);
    }
    #pragma unroll
    for (int j = 0; j < 16; j++) {
        float v = b3[j];
        #pragma unroll
        for (int k = 0; k < 16; k++) v = fmaf(h2[k], w3[k * 16 + j], v);
        h3[j] = fmaxf(v, 0.f);
    }
    float v = b4[0];
    #pragma unroll
    for (int k = 0; k < 16; k++) v = fmaf(h3[k], w4[k], v);
    float d = 1.f / (1.f + __expf(-v));

    if (valid) density_out[n] = d;
    float wsum = wave_reduce_sum(valid ? d : 0.f);
    if ((threadIdx.x & 63) == 0) unsafeAtomicAdd(densum, wsum);
}

// ---- pass 1: per-(n,chunk) affine composite  s_end = A + B*s_start --------
__global__ __launch_bounds__(256) void chunk_compose_kernel(
    const float* __restrict__ x, const float* __restrict__ alpha,
    const float* __restrict__ beta,
    float* __restrict__ Abuf, float* __restrict__ Bbuf)
{
    __shared__ float xs[CH];
    int c = blockIdx.y;
    xs[threadIdx.x] = x[c * CH + threadIdx.x] * LOG2E_K;
    __syncthreads();

    int n = blockIdx.x * 256 + threadIdx.x;
    int nn = (n < NM) ? n : NM - 1;
    float ka = alpha[nn] * LOG2E_K;
    float kb = beta[nn] * LOG2E_K;

    float A = 0.f, B = 1.f;
    #pragma unroll 8
    for (int i = 0; i < CH; i++) {
        float ku = xs[i];
        float e1 = __builtin_amdgcn_exp2f(ka - ku);   // exp(-1000*(u-alpha))
        float e2 = __builtin_amdgcn_exp2f(ku - kb);   // exp(-1000*(beta-u))
        float up = __builtin_amdgcn_rcpf(1.f + e1);
        float dn = __builtin_amdgcn_rcpf(1.f + e2);
        float aa = up - dn;
        float bb = (1.f - up) * (1.f - dn);
        A = fmaf(bb, A, aa);
        B *= bb;
    }
    if (n < NM) { Abuf[c * NM + n] = A; Bbuf[c * NM + n] = B; }
}

// ---- pass 2: sequential scan over the 16 chunk boundaries -----------------
__global__ __launch_bounds__(256) void chunk_scan_kernel(
    const float* __restrict__ init_raw,
    const float* __restrict__ Abuf, const float* __restrict__ Bbuf,
    float* __restrict__ sstart)
{
    int n = blockIdx.x * 256 + threadIdx.x;
    if (n >= NM) return;
    float s = tanhf(init_raw[n]);
    #pragma unroll
    for (int c = 0; c < NC; c++) {
        sstart[c * NM + n] = s;                     // state entering chunk c
        s = fmaf(Bbuf[c * NM + n], s, Abuf[c * NM + n]);
    }
}

// ---- pass 3: replay each chunk, store states (NO in-loop reduction) -------
__global__ __launch_bounds__(256) void states_kernel(
    const float* __restrict__ x, const float* __restrict__ alpha,
    const float* __restrict__ beta,
    const float* __restrict__ sstart,
    float* __restrict__ states)
{
    __shared__ float xs[CH];
    int c = blockIdx.y;
    xs[threadIdx.x] = x[c * CH + threadIdx.x] * LOG2E_K;
    __syncthreads();

    int n = blockIdx.x * 256 + threadIdx.x;
    bool valid = n < NM;
    int nn = valid ? n : NM - 1;
    float ka = alpha[nn] * LOG2E_K;
    float kb = beta[nn] * LOG2E_K;
    float s  = sstart[c * NM + nn];

    float* rowp = states + (size_t)c * CH * NM + n;

    #pragma unroll 8
    for (int i = 0; i < CH; i++) {
        float ku = xs[i];
        float e1 = __builtin_amdgcn_exp2f(ka - ku);
        float e2 = __builtin_amdgcn_exp2f(ku - kb);
        float up = __builtin_amdgcn_rcpf(1.f + e1);
        float dn = __builtin_amdgcn_rcpf(1.f + e2);
        float aa = up - dn;
        float bb = (1.f - up) * (1.f - dn);
        s = fmaf(bb, s, aa);
        if (valid) rowp[(size_t)i * NM] = s;
    }
}

// ---- pass 3b: msum[t] = sum_n density[n] * states[t][n], block per t ------
__global__ __launch_bounds__(256) void reduce_kernel(
    const float* __restrict__ states, const float* __restrict__ density,
    float* __restrict__ msum)
{
    int t = blockIdx.x;
    const float* __restrict__ row = states + (size_t)t * NM;
    float acc = 0.f;
    // coalesced dword loads (rows are only 4B-aligned, so no float4)
    for (int n = threadIdx.x; n < NM; n += 256)
        acc = fmaf(row[n], density[n], acc);
    acc = wave_reduce_sum(acc);
    __shared__ float wsums[4];
    if ((threadIdx.x & 63) == 0) wsums[threadIdx.x >> 6] = acc;
    __syncthreads();
    if (threadIdx.x == 0)
        msum[t] = wsums[0] + wsums[1] + wsums[2] + wsums[3];
}

// ---- pass 4: out[t] = m_scale*m + m_offset + h_scale*x --------------------
__global__ __launch_bounds__(256) void finalize_kernel(
    const float* __restrict__ x, const float* __restrict__ msum,
    const float* __restrict__ densum,
    const float* __restrict__ msr, const float* __restrict__ mor,
    const float* __restrict__ hsr, float* __restrict__ out)
{
    int t = blockIdx.x * 256 + threadIdx.x;
    if (t >= TT) return;
    float sig_ms = 1.f / (1.f + __expf(-msr[0]));
    float sig_mo = 1.f / (1.f + __expf(-mor[0]));
    float sig_hs = 1.f / (1.f + __expf(-hsr[0]));
    float m_scale  = 10.f * sig_ms;
    float m_offset = fmaf(20.f, sig_mo, -10.f);
    float h_scale  = 10.f * sig_hs;
    float m = msum[t] / densum[0];
    out[t] = fmaf(m_scale, m, m_offset) + h_scale * x[t];
}

extern "C" void kernel_launch(void* const* d_in, const int* in_sizes, int n_in,
                              void* d_out, int out_size, void* d_ws, size_t ws_size,
                              hipStream_t stream)
{
    // setup_inputs() dict order:
    const float* x    = (const float*)d_in[0];   // [4096]
    const float* alpha= (const float*)d_in[1];   // [20301]
    const float* beta = (const float*)d_in[2];   // [20301]
    const float* init = (const float*)d_in[3];   // [20301]
    const float* msr  = (const float*)d_in[4];   // [1]
    const float* mor  = (const float*)d_in[5];   // [1]
    const float* hsr  = (const float*)d_in[6];   // [1]
    const float* w1   = (const float*)d_in[7];   // [2,16]
    const float* b1   = (const float*)d_in[8];   // [16]
    const float* w2   = (const float*)d_in[9];   // [16,16]
    const float* b2   = (const float*)d_in[10];  // [16]
    const float* w3   = (const float*)d_in[11];  // [16,16]
    const float* b3   = (const float*)d_in[12];  // [16]
    const float* w4   = (const float*)d_in[13];  // [16,1]
    const float* b4   = (const float*)d_in[14];  // [1]

    float* out     = (float*)d_out;          // [TT]
    float* density = out + TT;               // [NM]
    float* states  = density + NM;           // [TT*NM]

    // workspace: msum[TT] | densum[1] | (pad) | sstart[NC*NM]
    float* msum   = (float*)d_ws;
    float* densum = msum + TT;
    float* sstart = msum + 8192;

    // (A,B) chunk composites stashed in the states region of d_out;
    // fully consumed by chunk_scan_kernel before states_kernel overwrites.
    float* Abuf = states;
    float* Bbuf = states + (size_t)NC * NM;

    // only densum needs zeroing now (msum is written, not accumulated)
    hipMemsetAsync(densum, 0, sizeof(float), stream);

    density_kernel<<<dim3(NBLK), dim3(256), 0, stream>>>(
        alpha, beta, w1, b1, w2, b2, w3, b3, w4, b4, density, densum);

    chunk_compose_kernel<<<dim3(NBLK, NC), dim3(256), 0, stream>>>(
        x, alpha, beta, Abuf, Bbuf);

    chunk_scan_kernel<<<dim3(NBLK), dim3(256), 0, stream>>>(
        init, Abuf, Bbuf, sstart);

    states_kernel<<<dim3(NBLK, NC), dim3(256), 0, stream>>>(
        x, alpha, beta, sstart, states);

    reduce_kernel<<<dim3(TT), dim3(256), 0, stream>>>(
        states, density, msum);

    finalize_kernel<<<dim3(TT / 256), dim3(256), 0, stream>>>(
        x, msum, densum, msr, mor, hsr, out);
}

// Round 3
// 486.048 us; speedup vs baseline: 1.5272x; 1.2218x over previous
//
#include <hip/hip_runtime.h>
#include <math.h>

// Problem constants (from reference)
#define NM 20301          // mesh points (201*202/2)
#define TT 4096           // time steps
#define NC 16             // chunks over T
#define CH 256            // steps per chunk = TT/NC
#define NBLK 80           // ceil(NM/256)
#define TPH 32            // t-phase width for fused LDS reduction
#define NPH (CH / TPH)    // 8 phases per chunk
#define LOG2E_K 1442.69504f   // 1000 * log2(e)  (temp = 0.001)

__device__ __forceinline__ float wave_reduce_sum(float w) {
    #pragma unroll
    for (int off = 32; off > 0; off >>= 1)
        w += __shfl_down(w, off, 64);
    return w;
}

// ---------------- density MLP: [N,2] -> 16 -> 16 -> 16 -> 1 ----------------
__global__ __launch_bounds__(256) void density_kernel(
    const float* __restrict__ alpha, const float* __restrict__ beta,
    const float* __restrict__ w1, const float* __restrict__ b1,
    const float* __restrict__ w2, const float* __restrict__ b2,
    const float* __restrict__ w3, const float* __restrict__ b3,
    const float* __restrict__ w4, const float* __restrict__ b4,
    float* __restrict__ density_out, float* __restrict__ densum)
{
    int n = blockIdx.x * 256 + threadIdx.x;
    bool valid = n < NM;
    int nn = valid ? n : NM - 1;
    float a = alpha[nn], b = beta[nn];

    float h1[16], h2[16], h3[16];
    #pragma unroll
    for (int j = 0; j < 16; j++) {
        float v = fmaf(a, w1[j], fmaf(b, w1[16 + j], b1[j]));
        h1[j] = fmaxf(v, 0.f);
    }
    #pragma unroll
    for (int j = 0; j < 16; j++) {
        float v = b2[j];
        #pragma unroll
        for (int k = 0; k < 16; k++) v = fmaf(h1[k], w2[k * 16 + j], v);
        h2[j] = fmaxf(v, 0.f);
    }
    #pragma unroll
    for (int j = 0; j < 16; j++) {
        float v = b3[j];
        #pragma unroll
        for (int k = 0; k < 16; k++) v = fmaf(h2[k], w3[k * 16 + j], v);
        h3[j] = fmaxf(v, 0.f);
    }
    float v = b4[0];
    #pragma unroll
    for (int k = 0; k < 16; k++) v = fmaf(h3[k], w4[k], v);
    float d = 1.f / (1.f + __expf(-v));

    if (valid) density_out[n] = d;
    float wsum = wave_reduce_sum(valid ? d : 0.f);
    if ((threadIdx.x & 63) == 0) unsafeAtomicAdd(densum, wsum);
}

// ---- pass 1: per-(n,chunk) affine composite  s_end = A + B*s_start --------
__global__ __launch_bounds__(256) void chunk_compose_kernel(
    const float* __restrict__ x, const float* __restrict__ alpha,
    const float* __restrict__ beta,
    float* __restrict__ Abuf, float* __restrict__ Bbuf)
{
    __shared__ float xs[CH];
    int c = blockIdx.y;
    xs[threadIdx.x] = x[c * CH + threadIdx.x] * LOG2E_K;
    __syncthreads();

    int n = blockIdx.x * 256 + threadIdx.x;
    int nn = (n < NM) ? n : NM - 1;
    float ka = alpha[nn] * LOG2E_K;
    float kb = beta[nn] * LOG2E_K;

    float A = 0.f, B = 1.f;
    #pragma unroll 8
    for (int i = 0; i < CH; i++) {
        float ku = xs[i];
        float e1 = __builtin_amdgcn_exp2f(ka - ku);   // exp(-1000*(u-alpha))
        float e2 = __builtin_amdgcn_exp2f(ku - kb);   // exp(-1000*(beta-u))
        float up = __builtin_amdgcn_rcpf(1.f + e1);
        float dn = __builtin_amdgcn_rcpf(1.f + e2);
        float aa = up - dn;
        float bb = (1.f - up) * (1.f - dn);
        A = fmaf(bb, A, aa);
        B *= bb;
    }
    if (n < NM) { Abuf[c * NM + n] = A; Bbuf[c * NM + n] = B; }
}

// ---- pass 2: sequential scan over the 16 chunk boundaries -----------------
__global__ __launch_bounds__(256) void chunk_scan_kernel(
    const float* __restrict__ init_raw,
    const float* __restrict__ Abuf, const float* __restrict__ Bbuf,
    float* __restrict__ sstart)
{
    int n = blockIdx.x * 256 + threadIdx.x;
    if (n >= NM) return;
    float s = tanhf(init_raw[n]);
    #pragma unroll
    for (int c = 0; c < NC; c++) {
        sstart[c * NM + n] = s;                     // state entering chunk c
        s = fmaf(Bbuf[c * NM + n], s, Abuf[c * NM + n]);
    }
}

// ---- pass 3: replay chunk, store states, FUSED block-level reduction ------
// LDS tile [256 n_local][TPH+1]: ds_write is fire-and-forget (not in the
// recurrence dependency chain, unlike R1's shuffle chain). Every TPH steps,
// two-stage LDS reduce -> one partial per (block, t); no atomics.
__global__ __launch_bounds__(256) void states_kernel(
    const float* __restrict__ x, const float* __restrict__ alpha,
    const float* __restrict__ beta, const float* __restrict__ density,
    const float* __restrict__ sstart,
    float* __restrict__ states, float* __restrict__ partials)
{
    __shared__ float xs[CH];
    __shared__ float tile[256 * (TPH + 1)];   // 33.8 KB, pad breaks conflicts
    __shared__ float lds2[TPH * 9];           // [t][8 groups + pad]

    int tid = threadIdx.x;
    int c = blockIdx.y;
    xs[tid] = x[c * CH + tid] * LOG2E_K;

    int n = blockIdx.x * 256 + tid;
    bool valid = n < NM;
    int nn = valid ? n : NM - 1;
    float ka = alpha[nn] * LOG2E_K;
    float kb = beta[nn] * LOG2E_K;
    float d  = valid ? density[n] : 0.f;
    float s  = sstart[c * NM + nn];
    __syncthreads();

    float* rowp  = states + (size_t)c * CH * NM + n;
    float* tslot = &tile[tid * (TPH + 1)];
    int tl = tid & 31;        // t within phase (for reduction role)
    int g  = tid >> 5;        // n-group (8 groups of 32)

    for (int p = 0; p < NPH; p++) {
        #pragma unroll
        for (int j = 0; j < TPH; j++) {
            int i = p * TPH + j;
            float ku = xs[i];
            float e1 = __builtin_amdgcn_exp2f(ka - ku);
            float e2 = __builtin_amdgcn_exp2f(ku - kb);
            float up = __builtin_amdgcn_rcpf(1.f + e1);
            float dn = __builtin_amdgcn_rcpf(1.f + e2);
            float aa = up - dn;
            float bb = (1.f - up) * (1.f - dn);
            s = fmaf(bb, s, aa);
            if (valid) rowp[(size_t)i * NM] = s;
            tslot[j] = d * s;
        }
        __syncthreads();
        // stage 1: each thread sums 32 n's for one t  (banks (k+tl)%32, free)
        float acc = 0.f;
        #pragma unroll
        for (int k = 0; k < 32; k++)
            acc += tile[(g * 32 + k) * (TPH + 1) + tl];
        lds2[tl * 9 + g] = acc;
        __syncthreads();
        // stage 2: 32 threads fold the 8 group partials, write coalesced
        if (tid < TPH) {
            float v = 0.f;
            #pragma unroll
            for (int g2 = 0; g2 < 8; g2++) v += lds2[tid * 9 + g2];
            partials[(size_t)blockIdx.x * TT + c * CH + p * TPH + tid] = v;
        }
    }
}

// ---- pass 4: fold 80 block-partials per t, apply scales -------------------
__global__ __launch_bounds__(256) void finalize_kernel(
    const float* __restrict__ x, const float* __restrict__ partials,
    const float* __restrict__ densum,
    const float* __restrict__ msr, const float* __restrict__ mor,
    const float* __restrict__ hsr, float* __restrict__ out)
{
    int t = blockIdx.x * 256 + threadIdx.x;
    if (t >= TT) return;
    float acc = 0.f;
    for (int bx = 0; bx < NBLK; bx++)
        acc += partials[(size_t)bx * TT + t];    // coalesced across lanes
    float sig_ms = 1.f / (1.f + __expf(-msr[0]));
    float sig_mo = 1.f / (1.f + __expf(-mor[0]));
    float sig_hs = 1.f / (1.f + __expf(-hsr[0]));
    float m_scale  = 10.f * sig_ms;
    float m_offset = fmaf(20.f, sig_mo, -10.f);
    float h_scale  = 10.f * sig_hs;
    float m = acc / densum[0];
    out[t] = fmaf(m_scale, m, m_offset) + h_scale * x[t];
}

extern "C" void kernel_launch(void* const* d_in, const int* in_sizes, int n_in,
                              void* d_out, int out_size, void* d_ws, size_t ws_size,
                              hipStream_t stream)
{
    // setup_inputs() dict order:
    const float* x    = (const float*)d_in[0];   // [4096]
    const float* alpha= (const float*)d_in[1];   // [20301]
    const float* beta = (const float*)d_in[2];   // [20301]
    const float* init = (const float*)d_in[3];   // [20301]
    const float* msr  = (const float*)d_in[4];   // [1]
    const float* mor  = (const float*)d_in[5];   // [1]
    const float* hsr  = (const float*)d_in[6];   // [1]
    const float* w1   = (const float*)d_in[7];   // [2,16]
    const float* b1   = (const float*)d_in[8];   // [16]
    const float* w2   = (const float*)d_in[9];   // [16,16]
    const float* b2   = (const float*)d_in[10];  // [16]
    const float* w3   = (const float*)d_in[11];  // [16,16]
    const float* b3   = (const float*)d_in[12];  // [16]
    const float* w4   = (const float*)d_in[13];  // [16,1]
    const float* b4   = (const float*)d_in[14];  // [1]

    float* out     = (float*)d_out;          // [TT]
    float* density = out + TT;               // [NM]
    float* states  = density + NM;           // [TT*NM]

    // workspace layout: densum[1] (pad to 256) | sstart[NC*NM] | partials[NBLK*TT]
    float* densum   = (float*)d_ws;
    float* sstart   = densum + 256;
    float* partials = sstart + NC * NM + 48;   // keep 256-float alignment-ish

    // (A,B) chunk composites stashed in the states region of d_out;
    // fully consumed by chunk_scan_kernel before states_kernel overwrites.
    float* Abuf = states;
    float* Bbuf = states + (size_t)NC * NM;

    hipMemsetAsync(densum, 0, sizeof(float), stream);

    density_kernel<<<dim3(NBLK), dim3(256), 0, stream>>>(
        alpha, beta, w1, b1, w2, b2, w3, b3, w4, b4, density, densum);

    chunk_compose_kernel<<<dim3(NBLK, NC), dim3(256), 0, stream>>>(
        x, alpha, beta, Abuf, Bbuf);

    chunk_scan_kernel<<<dim3(NBLK), dim3(256), 0, stream>>>(
        init, Abuf, Bbuf, sstart);

    states_kernel<<<dim3(NBLK, NC), dim3(256), 0, stream>>>(
        x, alpha, beta, density, sstart, states, partials);

    finalize_kernel<<<dim3(TT / 256), dim3(256), 0, stream>>>(
        x, partials, densum, msr, mor, hsr, out);
}